// Round 1
// baseline (294.333 us; speedup 1.0000x reference)
//
#include <hip/hip_runtime.h>
#include <math.h>

#define HH 6144
#define WW 6144
constexpr int G = 50;
constexpr int NCOPY = 64;
constexpr int NG = NCOPY * G; // 3200

// ws 4-byte-element layout:
// [0, NG)            hsum  (float)
// [NG, 2NG)          vsum  (float)
// [2NG, 3NG)         hcnt  (uint)
// [3NG, 4NG)         vcnt  (uint)
// [4NG, 4NG+NCOPY)   min   (uint, float bits; sp >= 0 so uint order == float order)

__device__ inline void ldsAddF(float* p, float v)    { __hip_atomic_fetch_add(p, v, __ATOMIC_RELAXED, __HIP_MEMORY_SCOPE_WORKGROUP); }
__device__ inline void ldsAddU(unsigned* p, unsigned v){ __hip_atomic_fetch_add(p, v, __ATOMIC_RELAXED, __HIP_MEMORY_SCOPE_WORKGROUP); }
__device__ inline void glbAddF(float* p, float v)    { __hip_atomic_fetch_add(p, v, __ATOMIC_RELAXED, __HIP_MEMORY_SCOPE_AGENT); }
__device__ inline void glbAddU(unsigned* p, unsigned v){ __hip_atomic_fetch_add(p, v, __ATOMIC_RELAXED, __HIP_MEMORY_SCOPE_AGENT); }

__global__ void crop_init(unsigned int* __restrict__ ws) {
  int i = blockIdx.x * 256 + threadIdx.x;
  if (i < 4 * NG) ws[i] = 0u;
  else if (i < 4 * NG + NCOPY) ws[i] = 0x7F800000u; // +inf bits
}

__launch_bounds__(384)
__global__ void crop_main(const float* __restrict__ sp,
                          const float* __restrict__ p_rmax,
                          const float* __restrict__ p_rmin,
                          const float* __restrict__ p_thmin,
                          const float* __restrict__ p_thmax,
                          const float* __restrict__ p_tvmin,
                          const float* __restrict__ p_tvmax,
                          float* __restrict__ wsf) {
  __shared__ int   xh[G];           // h boundaries for this row (nonincreasing in g)
  __shared__ float va[G], vb[G];    // vertical: y_g(x) = va[g] - x*vb[g]
  __shared__ float hsum[G + 1], vsum[G + 1];       // bin G = dropped (segment id 50)
  __shared__ unsigned int hcnt[G + 1], vcnt[G + 1];
  __shared__ float wmin[6];

  const int t  = threadIdx.x;
  const int y  = blockIdx.x;
  const int yp = min(max(y, 1), HH - 2);   // edge-effect fix == clamp of both coords

  for (int i = t; i < G + 1; i += 384) { hsum[i] = 0.f; vsum[i] = 0.f; hcnt[i] = 0u; vcnt[i] = 0u; }

  if (t < G) {
    double u    = (double)t / (double)(G - 1);
    double rmax = (double)p_rmax[0], rmin = (double)p_rmin[0];
    double rho  = rmax + (rmin - rmax) * u;
    double th   = (double)p_thmin[0] + ((double)p_thmax[0] - (double)p_thmin[0]) * u;
    double tv   = (double)p_tvmin[0] + ((double)p_tvmax[0] - (double)p_tvmin[0]) * u;
    double xg = rint(-(double)yp * tan(th) + rho / cos(th));   // half-even like jnp.round
    xg = fmin(fmax(xg, 0.0), (double)(WW - 1));
    xh[t] = (int)xg;
    va[t] = (float)(rho / sin(tv));
    vb[t] = (float)(cos(tv) / sin(tv));
  }
  __syncthreads();

  // Each thread owns 16 consecutive pixels (one 64B cache line): 4x float4.
  const int x0 = t * 16;
  const float4* p4 = (const float4*)(sp + (size_t)y * WW + x0);
  float4 q0 = p4[0], q1 = p4[1], q2 = p4[2], q3 = p4[3];
  float px[16] = { q0.x,q0.y,q0.z,q0.w, q1.x,q1.y,q1.z,q1.w,
                   q2.x,q2.y,q2.z,q2.w, q3.x,q3.y,q3.z,q3.w };

  const float fyp = (float)yp;
  const int xp0 = min(max(x0, 1), WW - 2);

  // h: lb = first g with xh[g] <= xp0  (array nonincreasing)
  int lo = 0, hi = G;
  while (lo < hi) { int m = (lo + hi) >> 1; if (xh[m] <= xp0) hi = m; else lo = m + 1; }
  int lb = lo;
  int nb = (lb > 0) ? xh[lb - 1] : 0x7FFFFFFF;

  // v: fb = first g with yv(g, xp0) <= yp  (yv nonincreasing in g)
  lo = 0; hi = G;
  while (lo < hi) {
    int m = (lo + hi) >> 1;
    float yv = rintf(fmaf(-(float)xp0, vb[m], va[m]));
    yv = fminf(fmaxf(yv, 0.f), (float)(HH - 1));
    if (yv <= fyp) hi = m; else lo = m + 1;
  }
  int fb = lo;

  int   sh = G - lb, sv = G - fb;
  float acch = 0.f, accv = 0.f;
  int   cnth = 0,   cntv = 0;
  float localmin = 3.4e38f;

#pragma unroll
  for (int k = 0; k < 16; ++k) {
    float v = px[k];
    localmin = fminf(localmin, v);
    int xp = min(max(x0 + k, 1), WW - 2);

    // horizontal segment id (nondecreasing along x)
    while (xp >= nb) { --lb; nb = (lb > 0) ? xh[lb - 1] : 0x7FFFFFFF; }
    int s = G - lb;
    if (s != sh) { ldsAddF(&hsum[sh], acch); ldsAddU(&hcnt[sh], (unsigned)cnth);
                   sh = s; acch = 0.f; cnth = 0; }
    acch += v; ++cnth;

    // vertical segment id (nondecreasing along x since yv decreases with x)
    while (fb > 0) {
      float yv = rintf(fmaf(-(float)xp, vb[fb - 1], va[fb - 1]));
      yv = fminf(fmaxf(yv, 0.f), (float)(HH - 1));
      if (yv <= fyp) --fb; else break;
    }
    s = G - fb;
    if (s != sv) { ldsAddF(&vsum[sv], accv); ldsAddU(&vcnt[sv], (unsigned)cntv);
                   sv = s; accv = 0.f; cntv = 0; }
    accv += v; ++cntv;
  }
  ldsAddF(&hsum[sh], acch); ldsAddU(&hcnt[sh], (unsigned)cnth);
  ldsAddF(&vsum[sv], accv); ldsAddU(&vcnt[sv], (unsigned)cntv);

  // block min reduce (6 waves)
  float m = localmin;
  for (int off = 32; off; off >>= 1) m = fminf(m, __shfl_down(m, off));
  if ((t & 63) == 0) wmin[t >> 6] = m;
  __syncthreads();

  const int copy = blockIdx.x & (NCOPY - 1);
  unsigned int* wsu = (unsigned int*)wsf;
  if (t == 0) {
    float mm = wmin[0];
    for (int i = 1; i < 6; ++i) mm = fminf(mm, wmin[i]);
    atomicMin(&wsu[4 * NG + copy], __float_as_uint(mm));
  }
  if (t < G) {                       // flush h bins 0..49 (bin 50 dropped, matches segment_sum)
    glbAddF(&wsf[copy * G + t], hsum[t]);
    glbAddU(&wsu[2 * NG + copy * G + t], hcnt[t]);
  } else if (t >= 64 && t < 64 + G) { // flush v bins
    int s = t - 64;
    glbAddF(&wsf[NG + copy * G + s], vsum[s]);
    glbAddU(&wsu[3 * NG + copy * G + s], vcnt[s]);
  }
}

__global__ void crop_final(const float* __restrict__ wsf,
                           const float* __restrict__ p_rmax,
                           const float* __restrict__ p_rmin,
                           const float* __restrict__ p_thmin,
                           const float* __restrict__ p_thmax,
                           const float* __restrict__ p_tvmin,
                           const float* __restrict__ p_tvmax,
                           float* __restrict__ out) {
  __shared__ double valh[G], valv[G];
  __shared__ float  sminv;
  const unsigned int* wsu = (const unsigned int*)wsf;
  const int t = threadIdx.x;

  if (t == 0) {
    unsigned int mb = 0x7F800000u;
    for (int i = 0; i < NCOPY; ++i) mb = min(mb, wsu[4 * NG + i]);
    sminv = __uint_as_float(mb);
  }
  __syncthreads();
  const double mv = (double)sminv;

  if (t < G) {
    double s = 0;  unsigned long long c = 0;
    double s2 = 0; unsigned long long c2 = 0;
    for (int i = 0; i < NCOPY; ++i) {
      s  += (double)wsf[i * G + t];       c  += wsu[2 * NG + i * G + t];
      s2 += (double)wsf[NG + i * G + t];  c2 += wsu[3 * NG + i * G + t];
    }
    valh[t] = s  - mv * (double)c;   // == segment_sum(nsp)*total (scale cancels in c)
    valv[t] = s2 - mv * (double)c2;
  }
  __syncthreads();

  if (t == 0) {
    double rmax = p_rmax[0], rmin = p_rmin[0];
    double thmin = p_thmin[0], thmax = p_thmax[0];
    double tvmin = p_tvmin[0], tvmax = p_tvmax[0];

    auto bounds = [&](const double* val, int& lowerI, int& upperI) {
      double tot = 0;
      for (int s = 0; s < G; ++s) tot += val[s];
      double c = 0; bool found = false; int last = -1; lowerI = 0;
      for (int s = 0; s < G; ++s) {
        c += val[s];
        double cc = c / tot;
        if (!found && cc >= 0.01) { lowerI = s; found = true; }
        if (cc <= 0.99) last = s;
      }
      upperI = (last < 0) ? (G + 1) : (last + 2);  // all-false reversed argmax -> 0 -> 51
    };
    int lh, uh, lv, uv;
    bounds(valh, lh, uh);
    bounds(valv, lv, uv);

    auto tn = [&](int i) { int idx = ((G - i) % G + G) % G; return idx; }; // a[-i]
    auto rho = [&](int i) { double u = (double)i / (G - 1); return rmax + (rmin - rmax) * u; };
    auto thf = [&](int i) { double u = (double)i / (G - 1); return thmin + (thmax - thmin) * u; };
    auto tvf = [&](int i) { double u = (double)i / (G - 1); return tvmin + (tvmax - tvmin) * u; };

    int ihmin = tn(lh), ihmax = tn(uh), ivmin = tn(lv), ivmax = tn(uv);
    double r_min_h = rho(ihmin), t_min_h = thf(ihmin);
    double r_max_h = rho(ihmax), t_max_h = thf(ihmax);
    double r_min_v = rho(ivmin), t_min_v = tvf(ivmin);
    double r_max_v = rho(ivmax), t_max_v = tvf(ivmax);

    auto inter = [&](double r1, double t1, double r2, double t2, float* o) {
      double det = cos(t1) * sin(t2) - cos(t2) * sin(t1);
      o[0] = (float)((r1 * sin(t2) - r2 * sin(t1)) / det);
      o[1] = (float)((r2 * cos(t1) - r1 * cos(t2)) / det);
    };
    inter(r_min_h, t_min_h, r_min_v, t_min_v, out + 0);
    inter(r_max_h, t_max_h, r_min_v, t_min_v, out + 2);
    inter(r_max_h, t_max_h, r_max_v, t_max_v, out + 4);
    inter(r_min_h, t_min_h, r_max_v, t_max_v, out + 6);
  }
}

extern "C" void kernel_launch(void* const* d_in, const int* in_sizes, int n_in,
                              void* d_out, int out_size, void* d_ws, size_t ws_size,
                              hipStream_t stream) {
  const float* sp    = (const float*)d_in[0];
  const float* rmax  = (const float*)d_in[1];
  const float* rmin  = (const float*)d_in[2];
  const float* thmin = (const float*)d_in[3];
  const float* thmax = (const float*)d_in[4];
  const float* tvmin = (const float*)d_in[5];
  const float* tvmax = (const float*)d_in[6];
  float* wsf = (float*)d_ws;
  float* outp = (float*)d_out;

  const int initN = 4 * NG + NCOPY;
  crop_init<<<(initN + 255) / 256, 256, 0, stream>>>((unsigned int*)d_ws);
  crop_main<<<HH, 384, 0, stream>>>(sp, rmax, rmin, thmin, thmax, tvmin, tvmax, wsf);
  crop_final<<<1, 64, 0, stream>>>(wsf, rmax, rmin, thmin, thmax, tvmin, tvmax, outp);
}

// Round 2
// 249.461 us; speedup vs baseline: 1.1799x; 1.1799x over previous
//
#include <hip/hip_runtime.h>
#include <math.h>

#define HH 6144
#define WW 6144
constexpr int G = 50;
constexpr int NCOPY = 64;
constexpr int NG = NCOPY * G; // 3200
constexpr int BIG = 0x0FFFFFFF;

// ws 4-byte-element layout:
// [0, NG)            hsum  (float)   copy-major: copy*G + g
// [NG, 2NG)          vsum  (float)
// [2NG, 3NG)         hcnt  (uint)
// [3NG, 4NG)         vcnt  (uint)
// [4NG, 4NG+NCOPY)   min   (uint, float bits; sp >= 0 so uint order == float order)

__device__ inline void ldsAddF(float* p, float v)      { __hip_atomic_fetch_add(p, v, __ATOMIC_RELAXED, __HIP_MEMORY_SCOPE_WORKGROUP); }
__device__ inline void ldsAddU(unsigned* p, unsigned v){ __hip_atomic_fetch_add(p, v, __ATOMIC_RELAXED, __HIP_MEMORY_SCOPE_WORKGROUP); }
__device__ inline void glbAddF(float* p, float v)      { __hip_atomic_fetch_add(p, v, __ATOMIC_RELAXED, __HIP_MEMORY_SCOPE_AGENT); }
__device__ inline void glbAddU(unsigned* p, unsigned v){ __hip_atomic_fetch_add(p, v, __ATOMIC_RELAXED, __HIP_MEMORY_SCOPE_AGENT); }

__global__ void crop_init(unsigned int* __restrict__ ws) {
  int i = blockIdx.x * 256 + threadIdx.x;
  if (i < 4 * NG) ws[i] = 0u;
  else if (i < 4 * NG + NCOPY) ws[i] = 0x7F800000u; // +inf bits
}

__launch_bounds__(384)
__global__ void crop_main(const float* __restrict__ sp,
                          const float* __restrict__ p_rmax,
                          const float* __restrict__ p_rmin,
                          const float* __restrict__ p_thmin,
                          const float* __restrict__ p_thmax,
                          const float* __restrict__ p_tvmin,
                          const float* __restrict__ p_tvmax,
                          float* __restrict__ wsf) {
  // integer pixel-space boundaries, nonincreasing in g:
  //   pixel x is "inside" line g  iff  x >= pxh[g] (resp pxv[g])
  __shared__ int pxh[G], pxv[G];
  __shared__ float hsum[G + 1], vsum[G + 1];       // bin G = dropped (segment id 50)
  __shared__ unsigned int hcnt[G + 1], vcnt[G + 1];
  __shared__ float wmin[6];

  const int t  = threadIdx.x;
  const int y  = blockIdx.x;
  const int yp = min(max(y, 1), HH - 2);   // edge-effect fix == clamp of both coords
  const float fyp = (float)yp;

  for (int i = t; i < G + 1; i += 384) { hsum[i] = 0.f; vsum[i] = 0.f; hcnt[i] = 0u; vcnt[i] = 0u; }

  // Issue the pixel loads up front (overlap with boundary setup).
  const int x0 = t * 16;
  const float4* p4 = (const float4*)(sp + (size_t)y * WW + x0);
  float4 q0 = p4[0], q1 = p4[1], q2 = p4[2], q3 = p4[3];

  if (t < G) {
    double u    = (double)t / (double)(G - 1);
    double rmax = (double)p_rmax[0], rmin = (double)p_rmin[0];
    double rho  = rmax + (rmin - rmax) * u;
    double th   = (double)p_thmin[0] + ((double)p_thmax[0] - (double)p_thmin[0]) * u;
    double tv   = (double)p_tvmin[0] + ((double)p_tvmax[0] - (double)p_tvmin[0]) * u;

    // horizontal family: integer column (same formula as round 1)
    double xg = rint(-(double)yp * tan(th) + rho / cos(th));   // half-even like jnp.round
    xg = fmin(fmax(xg, 0.0), (double)(WW - 1));
    int xi = (int)xg;
    pxh[t] = (xi <= 1) ? 0 : (xi >= WW - 1 ? BIG : xi);        // map through xp=clamp(x,1,W-2)

    // vertical family: binary-search the EXACT f32 per-pixel condition from round 1
    // cond(xp) = clamp(rintf(fmaf(-xp, vb, va)), 0, H-1) <= yp   (monotone in xp)
    float va = (float)(rho / sin(tv));
    float vb = (float)(cos(tv) / sin(tv));
    int lo = 1, hi = WW - 1;       // search xp in [1, W-2]; hi=W-1 sentinel = none
    while (lo < hi) {
      int m = (lo + hi) >> 1;
      float yv = rintf(fmaf(-(float)m, vb, va));
      yv = fminf(fmaxf(yv, 0.f), (float)(HH - 1));
      if (yv <= fyp) hi = m; else lo = m + 1;
    }
    pxv[t] = (lo >= WW - 1) ? BIG : (lo == 1 ? 0 : lo);
  }
  __syncthreads();

  float px[16] = { q0.x,q0.y,q0.z,q0.w, q1.x,q1.y,q1.z,q1.w,
                   q2.x,q2.y,q2.z,q2.w, q3.x,q3.y,q3.z,q3.w };

  // bin at x0 for each family: lb = first g with px*[g] <= x0 (arrays nonincreasing)
  int lo = 0, hi = G;
  while (lo < hi) { int m = (lo + hi) >> 1; if (pxh[m] <= x0) hi = m; else lo = m + 1; }
  const int lbh = lo;
  const int nbh = (lbh > 0) ? pxh[lbh - 1] : BIG;
  const int kh  = min(nbh - x0, 16);          // in [1,16]; 16 => no crossing in run

  lo = 0; hi = G;
  while (lo < hi) { int m = (lo + hi) >> 1; if (pxv[m] <= x0) hi = m; else lo = m + 1; }
  const int lbv = lo;
  const int nbv = (lbv > 0) ? pxv[lbv - 1] : BIG;
  const int kv  = min(nbv - x0, 16);

  const int sh = G - lbh, sv = G - lbv;

  // single pass: total S, prefix captures at kh/kv, running min
  float S = 0.f, Ah = 0.f, Av = 0.f, mn = 3.4e38f;
#pragma unroll
  for (int k = 0; k < 16; ++k) {
    float v = px[k];
    mn = fminf(mn, v);
    S += v;
    if (k + 1 == kh) Ah = S;   // prefix sum over pixels < kh (bin sh)
    if (k + 1 == kv) Av = S;
  }

  ldsAddF(&hsum[sh], Ah); ldsAddU(&hcnt[sh], (unsigned)kh);
  if (kh < 16) { ldsAddF(&hsum[sh + 1], S - Ah); ldsAddU(&hcnt[sh + 1], (unsigned)(16 - kh)); }
  ldsAddF(&vsum[sv], Av); ldsAddU(&vcnt[sv], (unsigned)kv);
  if (kv < 16) { ldsAddF(&vsum[sv + 1], S - Av); ldsAddU(&vcnt[sv + 1], (unsigned)(16 - kv)); }

  // block min reduce (6 waves)
  float m = mn;
  for (int off = 32; off; off >>= 1) m = fminf(m, __shfl_down(m, off));
  if ((t & 63) == 0) wmin[t >> 6] = m;
  __syncthreads();

  const int copy = blockIdx.x & (NCOPY - 1);
  unsigned int* wsu = (unsigned int*)wsf;
  if (t == 0) {
    float mm = wmin[0];
    for (int i = 1; i < 6; ++i) mm = fminf(mm, wmin[i]);
    atomicMin(&wsu[4 * NG + copy], __float_as_uint(mm));
  }
  if (t < G) {                        // flush h bins 0..49 (bin 50 dropped, matches segment_sum)
    glbAddF(&wsf[copy * G + t], hsum[t]);
    glbAddU(&wsu[2 * NG + copy * G + t], hcnt[t]);
  } else if (t >= 64 && t < 64 + G) { // flush v bins
    int s = t - 64;
    glbAddF(&wsf[NG + copy * G + s], vsum[s]);
    glbAddU(&wsu[3 * NG + copy * G + s], vcnt[s]);
  }
}

__launch_bounds__(512)
__global__ void crop_final(const float* __restrict__ wsf,
                           const float* __restrict__ p_rmax,
                           const float* __restrict__ p_rmin,
                           const float* __restrict__ p_thmin,
                           const float* __restrict__ p_thmax,
                           const float* __restrict__ p_tvmin,
                           const float* __restrict__ p_tvmax,
                           float* __restrict__ out) {
  __shared__ double psum[100][4];
  __shared__ unsigned int pcnt[100][4];
  __shared__ double val[100];          // [0..49]=h, [50..99]=v
  __shared__ float  sminv;
  const unsigned int* wsu = (const unsigned int*)wsf;
  const int t = threadIdx.x;

  // min over the 64 copy-slots: wave 0 does a shuffle reduce
  if (t < 64) {
    float v = __uint_as_float(wsu[4 * NG + t]);
    for (int off = 32; off; off >>= 1) v = fminf(v, __shfl_down(v, off));
    if (t == 0) sminv = v;
  }

  // parallel copy-reduction: 100 (fam,g) pairs x 4 chunks of 16 copies
  if (t < 400) {
    const int pair = t >> 2, chunk = t & 3;
    const int fam = pair >= G;          // 0=h, 1=v
    const int g = fam ? pair - G : pair;
    const int sumBase = fam ? NG : 0;
    const int cntBase = (2 + fam) * NG;
    double s = 0.0; unsigned int c = 0;
#pragma unroll
    for (int i = 0; i < 16; ++i) {
      const int copy = chunk * 16 + i;
      s += (double)wsf[sumBase + copy * G + g];
      c += wsu[cntBase + copy * G + g];
    }
    psum[pair][chunk] = s;
    pcnt[pair][chunk] = c;
  }
  __syncthreads();

  if (t < 100) {
    double s = psum[t][0] + psum[t][1] + psum[t][2] + psum[t][3];
    double c = (double)(pcnt[t][0] + pcnt[t][1] + pcnt[t][2] + pcnt[t][3]);
    val[t] = s - (double)sminv * c;   // == segment_sum(nsp)*total (scale cancels in cumsum)
  }
  __syncthreads();

  if (t == 0) {
    double rmax = p_rmax[0], rmin = p_rmin[0];
    double thmin = p_thmin[0], thmax = p_thmax[0];
    double tvmin = p_tvmin[0], tvmax = p_tvmax[0];

    auto bounds = [&](const double* v, int& lowerI, int& upperI) {
      double tot = 0;
      for (int s = 0; s < G; ++s) tot += v[s];
      double c = 0; bool found = false; int last = -1; lowerI = 0;
      for (int s = 0; s < G; ++s) {
        c += v[s];
        double cc = c / tot;
        if (!found && cc >= 0.01) { lowerI = s; found = true; }
        if (cc <= 0.99) last = s;
      }
      upperI = (last < 0) ? (G + 1) : (last + 2);  // all-false reversed argmax -> 0 -> 51
    };
    int lh, uh, lv, uv;
    bounds(&val[0], lh, uh);
    bounds(&val[G], lv, uv);

    auto tn  = [&](int i) { return ((G - i) % G + G) % G; };  // a[-i]
    auto rho = [&](int i) { double u = (double)i / (G - 1); return rmax + (rmin - rmax) * u; };
    auto thf = [&](int i) { double u = (double)i / (G - 1); return thmin + (thmax - thmin) * u; };
    auto tvf = [&](int i) { double u = (double)i / (G - 1); return tvmin + (tvmax - tvmin) * u; };

    int ihmin = tn(lh), ihmax = tn(uh), ivmin = tn(lv), ivmax = tn(uv);
    double r_min_h = rho(ihmin), t_min_h = thf(ihmin);
    double r_max_h = rho(ihmax), t_max_h = thf(ihmax);
    double r_min_v = rho(ivmin), t_min_v = tvf(ivmin);
    double r_max_v = rho(ivmax), t_max_v = tvf(ivmax);

    auto inter = [&](double r1, double t1, double r2, double t2, float* o) {
      double det = cos(t1) * sin(t2) - cos(t2) * sin(t1);
      o[0] = (float)((r1 * sin(t2) - r2 * sin(t1)) / det);
      o[1] = (float)((r2 * cos(t1) - r1 * cos(t2)) / det);
    };
    inter(r_min_h, t_min_h, r_min_v, t_min_v, out + 0);
    inter(r_max_h, t_max_h, r_min_v, t_min_v, out + 2);
    inter(r_max_h, t_max_h, r_max_v, t_max_v, out + 4);
    inter(r_min_h, t_min_h, r_max_v, t_max_v, out + 6);
  }
}

extern "C" void kernel_launch(void* const* d_in, const int* in_sizes, int n_in,
                              void* d_out, int out_size, void* d_ws, size_t ws_size,
                              hipStream_t stream) {
  const float* sp    = (const float*)d_in[0];
  const float* rmax  = (const float*)d_in[1];
  const float* rmin  = (const float*)d_in[2];
  const float* thmin = (const float*)d_in[3];
  const float* thmax = (const float*)d_in[4];
  const float* tvmin = (const float*)d_in[5];
  const float* tvmax = (const float*)d_in[6];
  float* wsf = (float*)d_ws;
  float* outp = (float*)d_out;

  const int initN = 4 * NG + NCOPY;
  crop_init<<<(initN + 255) / 256, 256, 0, stream>>>((unsigned int*)d_ws);
  crop_main<<<HH, 384, 0, stream>>>(sp, rmax, rmin, thmin, thmax, tvmin, tvmax, wsf);
  crop_final<<<1, 512, 0, stream>>>(wsf, rmax, rmin, thmin, thmax, tvmin, tvmax, outp);
}

// Round 3
// 247.794 us; speedup vs baseline: 1.1878x; 1.0067x over previous
//
#include <hip/hip_runtime.h>
#include <math.h>

#define HH 6144
#define WW 6144
constexpr int G = 50;
constexpr int NCOPY = 64;
constexpr int NG = NCOPY * G; // 3200
constexpr int BIG = 0x0FFFFFFF;
constexpr int C0 = 4 * NG + NCOPY; // 12864 (float idx); const tables live after accumulators

// ws 4-byte-element layout:
// [0, NG)             hsum  (float)   copy-major: copy*G + g
// [NG, 2NG)           vsum  (float)
// [2NG, 3NG)          hcnt  (uint)
// [3NG, 4NG)          vcnt  (uint)
// [4NG, 4NG+NCOPY)    min   (uint, float bits; sp >= 0 so uint order == float order)
// [C0, C0+100)        tan(th)   (50 doubles)
// [C0+100, C0+200)    rho/cos   (50 doubles)
// [C0+200, C0+250)    va        (50 floats)  y_g(x) = rint(va - x*vb)
// [C0+250, C0+300)    vb        (50 floats)

__device__ inline void ldsAddF(float* p, float v)      { __hip_atomic_fetch_add(p, v, __ATOMIC_RELAXED, __HIP_MEMORY_SCOPE_WORKGROUP); }
__device__ inline void ldsAddU(unsigned* p, unsigned v){ __hip_atomic_fetch_add(p, v, __ATOMIC_RELAXED, __HIP_MEMORY_SCOPE_WORKGROUP); }
__device__ inline void glbAddF(float* p, float v)      { __hip_atomic_fetch_add(p, v, __ATOMIC_RELAXED, __HIP_MEMORY_SCOPE_AGENT); }
__device__ inline void glbAddU(unsigned* p, unsigned v){ __hip_atomic_fetch_add(p, v, __ATOMIC_RELAXED, __HIP_MEMORY_SCOPE_AGENT); }

// memset accumulators + (block 0) per-g constants: trig is computed ONCE here,
// not per-row in crop_main (was ~3 f64 libm calls per row-block prologue).
__global__ void crop_init(unsigned int* __restrict__ ws,
                          const float* __restrict__ p_rmax,
                          const float* __restrict__ p_rmin,
                          const float* __restrict__ p_thmin,
                          const float* __restrict__ p_thmax,
                          const float* __restrict__ p_tvmin,
                          const float* __restrict__ p_tvmax) {
  int i = blockIdx.x * 256 + threadIdx.x;
  if (i < 4 * NG) ws[i] = 0u;
  else if (i < 4 * NG + NCOPY) ws[i] = 0x7F800000u; // +inf bits

  if (blockIdx.x == 0 && threadIdx.x < G) {
    int t = threadIdx.x;
    double u    = (double)t / (double)(G - 1);
    double rmax = (double)p_rmax[0], rmin = (double)p_rmin[0];
    double rho  = rmax + (rmin - rmax) * u;
    double th   = (double)p_thmin[0] + ((double)p_thmax[0] - (double)p_thmin[0]) * u;
    double tv   = (double)p_tvmin[0] + ((double)p_tvmax[0] - (double)p_tvmin[0]) * u;
    double* dT  = (double*)(ws + C0);
    double* dRC = (double*)(ws + C0 + 100);
    float*  fva = (float*)(ws + C0 + 200);
    float*  fvb = (float*)(ws + C0 + 250);
    dT[t]  = tan(th);
    dRC[t] = rho / cos(th);
    fva[t] = (float)(rho / sin(tv));
    fvb[t] = (float)(cos(tv) / sin(tv));
  }
}

__launch_bounds__(384)
__global__ void crop_main(const float* __restrict__ sp,
                          float* __restrict__ wsf) {
  // integer pixel-space boundaries, nonincreasing in g:
  //   pixel x is "inside" line g  iff  x >= pxh[g] (resp pxv[g])
  __shared__ int pxh[G], pxv[G];
  __shared__ float hsum[G + 1], vsum[G + 1];       // bin G = dropped (segment id 50)
  __shared__ unsigned int hcnt[G + 1], vcnt[G + 1];
  __shared__ float wmin[6];

  const int t  = threadIdx.x;
  const int y  = blockIdx.x;
  const int yp = min(max(y, 1), HH - 2);   // edge-effect fix == clamp of both coords
  const float fyp = (float)yp;

  // Issue the pixel loads up front (overlap with boundary setup).
  const int x0 = t * 16;
  const float4* p4 = (const float4*)(sp + (size_t)y * WW + x0);
  float4 q0 = p4[0], q1 = p4[1], q2 = p4[2], q3 = p4[3];

  for (int i = t; i < G + 1; i += 384) { hsum[i] = 0.f; vsum[i] = 0.f; hcnt[i] = 0u; vcnt[i] = 0u; }

  if (t < G) {
    const unsigned int* wsu = (const unsigned int*)wsf;
    const double* dT  = (const double*)(wsu + C0);
    const double* dRC = (const double*)(wsu + C0 + 100);
    const float*  fva = (const float*)(wsu + C0 + 200);
    const float*  fvb = (const float*)(wsu + C0 + 250);

    // horizontal family: integer column (same f64 math as before, trig hoisted)
    double xg = rint(fma(-(double)yp, dT[t], dRC[t]));  // half-even like jnp.round
    xg = fmin(fmax(xg, 0.0), (double)(WW - 1));
    int xi = (int)xg;
    pxh[t] = (xi <= 1) ? 0 : (xi >= WW - 1 ? BIG : xi); // map through xp=clamp(x,1,W-2)

    // vertical family: binary-search the EXACT f32 per-pixel condition
    // cond(xp) = clamp(rintf(fmaf(-xp, vb, va)), 0, H-1) <= yp   (monotone in xp)
    float va = fva[t], vb = fvb[t];
    int lo = 1, hi = WW - 1;       // search xp in [1, W-2]; hi=W-1 sentinel = none
    while (lo < hi) {
      int m = (lo + hi) >> 1;
      float yv = rintf(fmaf(-(float)m, vb, va));
      yv = fminf(fmaxf(yv, 0.f), (float)(HH - 1));
      if (yv <= fyp) hi = m; else lo = m + 1;
    }
    pxv[t] = (lo >= WW - 1) ? BIG : (lo == 1 ? 0 : lo);
  }
  __syncthreads();

  float px[16] = { q0.x,q0.y,q0.z,q0.w, q1.x,q1.y,q1.z,q1.w,
                   q2.x,q2.y,q2.z,q2.w, q3.x,q3.y,q3.z,q3.w };

  // bin at x0 for each family: lb = first g with px*[g] <= x0 (arrays nonincreasing)
  int lo = 0, hi = G;
  while (lo < hi) { int m = (lo + hi) >> 1; if (pxh[m] <= x0) hi = m; else lo = m + 1; }
  const int lbh = lo;
  const int nbh = (lbh > 0) ? pxh[lbh - 1] : BIG;
  const int kh  = min(nbh - x0, 16);          // in [1,16]; 16 => no crossing in run

  lo = 0; hi = G;
  while (lo < hi) { int m = (lo + hi) >> 1; if (pxv[m] <= x0) hi = m; else lo = m + 1; }
  const int lbv = lo;
  const int nbv = (lbv > 0) ? pxv[lbv - 1] : BIG;
  const int kv  = min(nbv - x0, 16);

  const int sh = G - lbh, sv = G - lbv;

  // single pass: total S, prefix captures at kh/kv, running min
  float S = 0.f, Ah = 0.f, Av = 0.f, mn = 3.4e38f;
#pragma unroll
  for (int k = 0; k < 16; ++k) {
    float v = px[k];
    mn = fminf(mn, v);
    S += v;
    if (k + 1 == kh) Ah = S;   // prefix sum over pixels < kh (bin sh)
    if (k + 1 == kv) Av = S;
  }

  ldsAddF(&hsum[sh], Ah); ldsAddU(&hcnt[sh], (unsigned)kh);
  if (kh < 16) { ldsAddF(&hsum[sh + 1], S - Ah); ldsAddU(&hcnt[sh + 1], (unsigned)(16 - kh)); }
  ldsAddF(&vsum[sv], Av); ldsAddU(&vcnt[sv], (unsigned)kv);
  if (kv < 16) { ldsAddF(&vsum[sv + 1], S - Av); ldsAddU(&vcnt[sv + 1], (unsigned)(16 - kv)); }

  // block min reduce (6 waves)
  float m = mn;
  for (int off = 32; off; off >>= 1) m = fminf(m, __shfl_down(m, off));
  if ((t & 63) == 0) wmin[t >> 6] = m;
  __syncthreads();

  const int copy = blockIdx.x & (NCOPY - 1);
  unsigned int* wsu = (unsigned int*)wsf;
  if (t == 0) {
    float mm = wmin[0];
    for (int i = 1; i < 6; ++i) mm = fminf(mm, wmin[i]);
    atomicMin(&wsu[4 * NG + copy], __float_as_uint(mm));
  }
  if (t < G) {                        // flush h bins 0..49 (bin 50 dropped, matches segment_sum)
    glbAddF(&wsf[copy * G + t], hsum[t]);
    glbAddU(&wsu[2 * NG + copy * G + t], hcnt[t]);
  } else if (t >= 64 && t < 64 + G) { // flush v bins
    int s = t - 64;
    glbAddF(&wsf[NG + copy * G + s], vsum[s]);
    glbAddU(&wsu[3 * NG + copy * G + s], vcnt[s]);
  }
}

__launch_bounds__(512)
__global__ void crop_final(const float* __restrict__ wsf,
                           const float* __restrict__ p_rmax,
                           const float* __restrict__ p_rmin,
                           const float* __restrict__ p_thmin,
                           const float* __restrict__ p_thmax,
                           const float* __restrict__ p_tvmin,
                           const float* __restrict__ p_tvmax,
                           float* __restrict__ out) {
  __shared__ double psum[100][4];
  __shared__ unsigned int pcnt[100][4];
  __shared__ double val[100];          // [0..49]=h, [50..99]=v
  __shared__ float  sminv;
  const unsigned int* wsu = (const unsigned int*)wsf;
  const int t = threadIdx.x;

  // min over the 64 copy-slots: wave 0 does a shuffle reduce
  if (t < 64) {
    float v = __uint_as_float(wsu[4 * NG + t]);
    for (int off = 32; off; off >>= 1) v = fminf(v, __shfl_down(v, off));
    if (t == 0) sminv = v;
  }

  // parallel copy-reduction: 100 (fam,g) pairs x 4 chunks of 16 copies
  if (t < 400) {
    const int pair = t >> 2, chunk = t & 3;
    const int fam = pair >= G;          // 0=h, 1=v
    const int g = fam ? pair - G : pair;
    const int sumBase = fam ? NG : 0;
    const int cntBase = (2 + fam) * NG;
    double s = 0.0; unsigned int c = 0;
#pragma unroll
    for (int i = 0; i < 16; ++i) {
      const int copy = chunk * 16 + i;
      s += (double)wsf[sumBase + copy * G + g];
      c += wsu[cntBase + copy * G + g];
    }
    psum[pair][chunk] = s;
    pcnt[pair][chunk] = c;
  }
  __syncthreads();

  if (t < 100) {
    double s = psum[t][0] + psum[t][1] + psum[t][2] + psum[t][3];
    double c = (double)(pcnt[t][0] + pcnt[t][1] + pcnt[t][2] + pcnt[t][3]);
    val[t] = s - (double)sminv * c;   // == segment_sum(nsp)*total (scale cancels in cumsum)
  }
  __syncthreads();

  if (t == 0) {
    double rmax = p_rmax[0], rmin = p_rmin[0];
    double thmin = p_thmin[0], thmax = p_thmax[0];
    double tvmin = p_tvmin[0], tvmax = p_tvmax[0];

    auto bounds = [&](const double* v, int& lowerI, int& upperI) {
      double tot = 0;
      for (int s = 0; s < G; ++s) tot += v[s];
      double c = 0; bool found = false; int last = -1; lowerI = 0;
      for (int s = 0; s < G; ++s) {
        c += v[s];
        double cc = c / tot;
        if (!found && cc >= 0.01) { lowerI = s; found = true; }
        if (cc <= 0.99) last = s;
      }
      upperI = (last < 0) ? (G + 1) : (last + 2);  // all-false reversed argmax -> 0 -> 51
    };
    int lh, uh, lv, uv;
    bounds(&val[0], lh, uh);
    bounds(&val[G], lv, uv);

    auto tn  = [&](int i) { return ((G - i) % G + G) % G; };  // a[-i]
    auto rho = [&](int i) { double u = (double)i / (G - 1); return rmax + (rmin - rmax) * u; };
    auto thf = [&](int i) { double u = (double)i / (G - 1); return thmin + (thmax - thmin) * u; };
    auto tvf = [&](int i) { double u = (double)i / (G - 1); return tvmin + (tvmax - tvmin) * u; };

    int ihmin = tn(lh), ihmax = tn(uh), ivmin = tn(lv), ivmax = tn(uv);
    double r_min_h = rho(ihmin), t_min_h = thf(ihmin);
    double r_max_h = rho(ihmax), t_max_h = thf(ihmax);
    double r_min_v = rho(ivmin), t_min_v = tvf(ivmin);
    double r_max_v = rho(ivmax), t_max_v = tvf(ivmax);

    auto inter = [&](double r1, double t1, double r2, double t2, float* o) {
      double det = cos(t1) * sin(t2) - cos(t2) * sin(t1);
      o[0] = (float)((r1 * sin(t2) - r2 * sin(t1)) / det);
      o[1] = (float)((r2 * cos(t1) - r1 * cos(t2)) / det);
    };
    inter(r_min_h, t_min_h, r_min_v, t_min_v, out + 0);
    inter(r_max_h, t_max_h, r_min_v, t_min_v, out + 2);
    inter(r_max_h, t_max_h, r_max_v, t_max_v, out + 4);
    inter(r_min_h, t_min_h, r_max_v, t_max_v, out + 6);
  }
}

extern "C" void kernel_launch(void* const* d_in, const int* in_sizes, int n_in,
                              void* d_out, int out_size, void* d_ws, size_t ws_size,
                              hipStream_t stream) {
  const float* sp    = (const float*)d_in[0];
  const float* rmax  = (const float*)d_in[1];
  const float* rmin  = (const float*)d_in[2];
  const float* thmin = (const float*)d_in[3];
  const float* thmax = (const float*)d_in[4];
  const float* tvmin = (const float*)d_in[5];
  const float* tvmax = (const float*)d_in[6];
  float* wsf = (float*)d_ws;
  float* outp = (float*)d_out;

  const int initN = 4 * NG + NCOPY;
  crop_init<<<(initN + 255) / 256, 256, 0, stream>>>((unsigned int*)d_ws,
                                                     rmax, rmin, thmin, thmax, tvmin, tvmax);
  crop_main<<<HH, 384, 0, stream>>>(sp, wsf);
  crop_final<<<1, 512, 0, stream>>>(wsf, rmax, rmin, thmin, thmax, tvmin, tvmax, outp);
}